// Round 18
// baseline (99.176 us; speedup 1.0000x reference)
//
#include <hip/hip_runtime.h>
#include <math.h>

#define LOG_2PI_F 1.8378770664093453f
#define EPS_F 1e-10f
#define NB 32        // batches
#define CV 512       // components per batch (C*V)
#define PPW 4        // points per wave  (round 17: 8 -> 4, 2x TLP)
#define KPL 8        // comps per lane = CV / 64

// Round-17 structure with PPW=4: 8192 waves, shorter serial body per wave.
// Params in registers (float2 mu loads); 2-point interleaved LSE; x-loads
// for all 4 points hoisted ahead of the compute loop.
__global__ __launch_bounds__(256)
__attribute__((amdgpu_waves_per_eu(2, 4)))
void capsule_main(
    const float* __restrict__ x,
    const float* __restrict__ vote,
    const float* __restrict__ scales,
    const float* __restrict__ log_pres,
    const int* __restrict__ batch,
    float* __restrict__ out_pe,   // [NB], zeroed; boundary waves atomic here
    float* __restrict__ wsum,     // [n_waves], unique slot per wave
    int n_pts)
{
    const int tid  = threadIdx.x;
    const int lane = tid & 63;
    const int wloc = __builtin_amdgcn_readfirstlane(tid >> 6);
    const int wave = blockIdx.x * 4 + wloc;
    const int p0   = wave * PPW;
    if (p0 >= n_pts) return;

    int pidx = p0 + (lane & (PPW - 1));
    if (pidx >= n_pts) pidx = n_pts - 1;
    const int  pbq     = batch[pidx];
    const int  b0      = __builtin_amdgcn_readfirstlane(pbq);
    const bool uniform = (__ballot(pbq == b0) == ~0ull);

    // packed per-comp params in registers: a* = mu_d * inv, inv, coef
    float a0[KPL], a1[KPL], a2[KPL], a3[KPL], a4[KPL], a5[KPL];
    float ainv[KPL], acoef[KPL];

    auto load_params = [&](int b) {
        #pragma unroll
        for (int j = 0; j < KPL; ++j) {
            const int c = b * CV + lane + 64 * j;   // coalesced across lanes
            float s   = fmaxf(scales[c], EPS_F);
            float inv = 1.0f / s;
            // vote + c*6 floats = c*24 bytes -> 8B-aligned: float2 loads
            const float2* mu2 = (const float2*)(vote + (size_t)c * 6);
            float2 m01 = mu2[0], m23 = mu2[1], m45 = mu2[2];
            a0[j] = m01.x * inv;
            a1[j] = m01.y * inv;
            a2[j] = m23.x * inv;
            a3[j] = m23.y * inv;
            a4[j] = m45.x * inv;
            a5[j] = m45.y * inv;
            ainv[j]  = inv;
            acoef[j] = log_pres[c] - 6.0f * __logf(s) - 3.0f * LOG_2PI_F;
        }
    };

    load_params(b0);

    auto logits = [&](const float* xv, float* l) {
        #pragma unroll
        for (int j = 0; j < KPL; ++j) {
            float z, acc;
            z = fmaf(xv[0], ainv[j], -a0[j]); acc = z * z;
            z = fmaf(xv[1], ainv[j], -a1[j]); acc = fmaf(z, z, acc);
            z = fmaf(xv[2], ainv[j], -a2[j]); acc = fmaf(z, z, acc);
            z = fmaf(xv[3], ainv[j], -a3[j]); acc = fmaf(z, z, acc);
            z = fmaf(xv[4], ainv[j], -a4[j]); acc = fmaf(z, z, acc);
            z = fmaf(xv[5], ainv[j], -a5[j]); acc = fmaf(z, z, acc);
            l[j] = fmaf(acc, -0.5f, acoef[j]);
        }
    };

    auto local_max = [](const float* l) {
        return fmaxf(fmaxf(fmaxf(l[0], l[1]), fmaxf(l[2], l[3])),
                     fmaxf(fmaxf(l[4], l[5]), fmaxf(l[6], l[7])));
    };

    if (uniform && p0 + PPW <= n_pts) {
        // hoist all x loads (wave-uniform -> scalar pipe), no loads in loop
        float xx[PPW][6];
        #pragma unroll
        for (int q = 0; q < PPW; ++q) {
            const float* xp = x + (size_t)(p0 + q) * 6;
            #pragma unroll
            for (int d = 0; d < 6; ++d) xx[q][d] = xp[d];
        }

        float wavesum = 0.0f;
        #pragma unroll
        for (int q = 0; q < PPW; q += 2) {
            float la[KPL], lb[KPL];
            logits(xx[q],     la);
            logits(xx[q + 1], lb);

            float ma = local_max(la);
            float mb = local_max(lb);
            #pragma unroll
            for (int off = 1; off <= 32; off <<= 1) {
                float ta = __shfl_xor(ma, off, 64);
                float tb = __shfl_xor(mb, off, 64);
                ma = fmaxf(ma, ta);
                mb = fmaxf(mb, tb);
            }

            float ea = (__expf(la[0] - ma) + __expf(la[1] - ma))
                     + (__expf(la[2] - ma) + __expf(la[3] - ma))
                     + (__expf(la[4] - ma) + __expf(la[5] - ma))
                     + (__expf(la[6] - ma) + __expf(la[7] - ma));
            float eb = (__expf(lb[0] - mb) + __expf(lb[1] - mb))
                     + (__expf(lb[2] - mb) + __expf(lb[3] - mb))
                     + (__expf(lb[4] - mb) + __expf(lb[5] - mb))
                     + (__expf(lb[6] - mb) + __expf(lb[7] - mb));
            #pragma unroll
            for (int off = 1; off <= 32; off <<= 1) {
                float ta = __shfl_xor(ea, off, 64);
                float tb = __shfl_xor(eb, off, 64);
                ea += ta;
                eb += tb;
            }

            wavesum += (ma + __logf(ea)) + (mb + __logf(eb));
        }
        if (lane == 0) wsum[wave] = wavesum;   // unique slot, no RMW
    } else {
        // rare: batch-boundary or ragged-tail wave -> per-point, atomics
        if (lane == 0) wsum[wave] = 0.0f;
        int cur_b = b0;
        for (int q = 0; q < PPW; ++q) {
            const int p = p0 + q;
            if (p >= n_pts) break;
            const int pb = batch[p];
            if (pb != cur_b) { load_params(pb); cur_b = pb; }
            float xv[6];
            const float* xp = x + (size_t)p * 6;
            #pragma unroll
            for (int d = 0; d < 6; ++d) xv[d] = xp[d];
            float l[KPL];
            logits(xv, l);
            float lm = local_max(l);
            #pragma unroll
            for (int off = 1; off <= 32; off <<= 1)
                lm = fmaxf(lm, __shfl_xor(lm, off, 64));
            float es = 0.0f;
            #pragma unroll
            for (int j = 0; j < KPL; ++j) es += __expf(l[j] - lm);
            #pragma unroll
            for (int off = 1; off <= 32; off <<= 1)
                es += __shfl_xor(es, off, 64);
            float lp = lm + __logf(es);
            if (lane == 0) atomicAdd(&out_pe[cur_b], lp);
        }
    }
}

// One block: reduce wsum[] per batch, fold boundary atomics, write mean.
__global__ __launch_bounds__(1024) void final_kernel(
    const float* __restrict__ wsum,
    const int* __restrict__ batch,
    float* __restrict__ d_out,   // [0]=mean, [1..32]=per-example
    int n_waves, int n_pts)
{
    __shared__ float part[NB];
    const int t = threadIdx.x;
    if (t < NB) part[t] = 0.0f;
    __syncthreads();

    for (int w = t; w < n_waves; w += 1024) {
        float s = wsum[w];                       // 0 for boundary waves
        int   pi = w * PPW;
        if (pi >= n_pts) pi = n_pts - 1;
        atomicAdd(&part[batch[pi]], s);          // LDS atomic, 32 bins
    }
    __syncthreads();

    if (t < 64) {
        float v = 0.0f;
        if (t < NB) {
            v = d_out[1 + t] + part[t];          // fold boundary atomics
            d_out[1 + t] = v;
        }
        #pragma unroll
        for (int off = 32; off >= 1; off >>= 1) v += __shfl_xor(v, off, 64);
        if (t == 0) d_out[0] = v * (1.0f / NB);
    }
}

extern "C" void kernel_launch(void* const* d_in, const int* in_sizes, int n_in,
                              void* d_out, int out_size, void* d_ws, size_t ws_size,
                              hipStream_t stream) {
    const float* x        = (const float*)d_in[0];
    const float* vote     = (const float*)d_in[1];
    const float* scales   = (const float*)d_in[2];
    const float* log_pres = (const float*)d_in[3];
    const int*   batch    = (const int*)d_in[4];
    float* out = (float*)d_out;
    float* ws  = (float*)d_ws;

    int n_pts   = in_sizes[0] / 6;
    int n_waves = (n_pts + PPW - 1) / PPW;

    // out re-poisoned to 0xAA before every timed call -> zero it (capture-legal)
    hipMemsetAsync(d_out, 0, (size_t)out_size * sizeof(float), stream);

    int n_blocks = (n_waves + 3) / 4;        // 4 waves (256 threads) per block
    capsule_main<<<n_blocks, 256, 0, stream>>>(x, vote, scales, log_pres, batch,
                                               out + 1, ws, n_pts);

    final_kernel<<<1, 1024, 0, stream>>>(ws, batch, out, n_waves, n_pts);
}

// Round 19
// 92.510 us; speedup vs baseline: 1.0721x; 1.0721x over previous
//
#include <hip/hip_runtime.h>
#include <math.h>

#define LOG_2PI_F 1.8378770664093453f
#define EPS_F 1e-10f
#define NB 32        // batches
#define CV 512       // components per batch (C*V)
#define PPW 8        // points per wave (best measured)
#define PPB 32       // points per block (4 waves)
#define KPL 8        // comps per lane = CV / 64

// Round-17 hot path + block-level LDS staging of RAW params:
// one coalesced float4 copy per lane stages vote/scales/log_pres for the
// block's batch; each lane then builds its 8-comp packed registers from LDS.
// Cuts the per-wave param phase (measured ~8us of 31 at PPW=8, round 18)
// ~4x in global traffic and ~40x in vmem issue count.
__global__ __launch_bounds__(256)
__attribute__((amdgpu_waves_per_eu(2, 4)))
void capsule_main(
    const float* __restrict__ x,
    const float* __restrict__ vote,
    const float* __restrict__ scales,
    const float* __restrict__ log_pres,
    const int* __restrict__ batch,
    float* __restrict__ out_pe,   // [NB], zeroed; boundary waves atomic here
    float* __restrict__ wsum,     // [n_waves], unique slot per wave
    int n_pts)
{
    __shared__ float s_vote[CV * 6];    // 12 KB
    __shared__ float s_sc[CV];          // 2 KB
    __shared__ float s_lp[CV];          // 2 KB

    const int tid  = threadIdx.x;
    const int lane = tid & 63;
    const int wloc = __builtin_amdgcn_readfirstlane(tid >> 6);
    const int wave = blockIdx.x * 4 + wloc;
    const int p0   = wave * PPW;

    // ---- stage raw params for the block's batch (coalesced float4) ----
    int pblk = blockIdx.x * PPB;
    if (pblk >= n_pts) pblk = n_pts - 1;
    const int bblk = batch[pblk];
    {
        const float4* gv = (const float4*)(vote + (size_t)bblk * CV * 6);
        float4* sv = (float4*)s_vote;
        #pragma unroll
        for (int i = 0; i < 3; ++i)            // 768 float4s / 256 threads
            sv[tid + 256 * i] = gv[tid + 256 * i];
        const float4* gs = (const float4*)(scales + (size_t)bblk * CV);
        const float4* gl = (const float4*)(log_pres + (size_t)bblk * CV);
        if (tid < 128) {
            ((float4*)s_sc)[tid] = gs[tid];
            ((float4*)s_lp)[tid] = gl[tid];
        }
    }
    __syncthreads();

    if (p0 >= n_pts) return;

    int pidx = p0 + (lane & (PPW - 1));
    if (pidx >= n_pts) pidx = n_pts - 1;
    const int  pbq     = batch[pidx];
    const int  b0      = __builtin_amdgcn_readfirstlane(pbq);
    const bool uniform = (__ballot(pbq == b0) == ~0ull) && (b0 == bblk);

    // packed per-comp params in registers: a* = mu_d * inv, inv, coef
    float a0[KPL], a1[KPL], a2[KPL], a3[KPL], a4[KPL], a5[KPL];
    float ainv[KPL], acoef[KPL];

    // build packed regs from LDS (hot) or global (boundary fallback)
    auto build_from_lds = [&]() {
        #pragma unroll
        for (int j = 0; j < KPL; ++j) {
            const int c = lane + 64 * j;
            float s   = fmaxf(s_sc[c], EPS_F);
            float inv = 1.0f / s;
            const float* mu = s_vote + c * 6;
            a0[j] = mu[0] * inv;
            a1[j] = mu[1] * inv;
            a2[j] = mu[2] * inv;
            a3[j] = mu[3] * inv;
            a4[j] = mu[4] * inv;
            a5[j] = mu[5] * inv;
            ainv[j]  = inv;
            acoef[j] = s_lp[c] - 6.0f * __logf(s) - 3.0f * LOG_2PI_F;
        }
    };
    auto build_from_global = [&](int b) {
        #pragma unroll
        for (int j = 0; j < KPL; ++j) {
            const int c = b * CV + lane + 64 * j;
            float s   = fmaxf(scales[c], EPS_F);
            float inv = 1.0f / s;
            const float2* mu2 = (const float2*)(vote + (size_t)c * 6);
            float2 m01 = mu2[0], m23 = mu2[1], m45 = mu2[2];
            a0[j] = m01.x * inv;
            a1[j] = m01.y * inv;
            a2[j] = m23.x * inv;
            a3[j] = m23.y * inv;
            a4[j] = m45.x * inv;
            a5[j] = m45.y * inv;
            ainv[j]  = inv;
            acoef[j] = log_pres[c] - 6.0f * __logf(s) - 3.0f * LOG_2PI_F;
        }
    };

    auto logits = [&](const float* xv, float* l) {
        #pragma unroll
        for (int j = 0; j < KPL; ++j) {
            float z, acc;
            z = fmaf(xv[0], ainv[j], -a0[j]); acc = z * z;
            z = fmaf(xv[1], ainv[j], -a1[j]); acc = fmaf(z, z, acc);
            z = fmaf(xv[2], ainv[j], -a2[j]); acc = fmaf(z, z, acc);
            z = fmaf(xv[3], ainv[j], -a3[j]); acc = fmaf(z, z, acc);
            z = fmaf(xv[4], ainv[j], -a4[j]); acc = fmaf(z, z, acc);
            z = fmaf(xv[5], ainv[j], -a5[j]); acc = fmaf(z, z, acc);
            l[j] = fmaf(acc, -0.5f, acoef[j]);
        }
    };
    auto local_max = [](const float* l) {
        return fmaxf(fmaxf(fmaxf(l[0], l[1]), fmaxf(l[2], l[3])),
                     fmaxf(fmaxf(l[4], l[5]), fmaxf(l[6], l[7])));
    };

    if (uniform && p0 + PPW <= n_pts) {
        build_from_lds();

        // hoist all x loads (wave-uniform -> scalar pipe)
        float xx[PPW][6];
        #pragma unroll
        for (int q = 0; q < PPW; ++q) {
            const float* xp = x + (size_t)(p0 + q) * 6;
            #pragma unroll
            for (int d = 0; d < 6; ++d) xx[q][d] = xp[d];
        }

        float wavesum = 0.0f;
        #pragma unroll
        for (int q = 0; q < PPW; q += 2) {
            float la[KPL], lb[KPL];
            logits(xx[q],     la);
            logits(xx[q + 1], lb);

            float ma = local_max(la);
            float mb = local_max(lb);
            #pragma unroll
            for (int off = 1; off <= 32; off <<= 1) {
                float ta = __shfl_xor(ma, off, 64);
                float tb = __shfl_xor(mb, off, 64);
                ma = fmaxf(ma, ta);
                mb = fmaxf(mb, tb);
            }

            float ea = (__expf(la[0] - ma) + __expf(la[1] - ma))
                     + (__expf(la[2] - ma) + __expf(la[3] - ma))
                     + (__expf(la[4] - ma) + __expf(la[5] - ma))
                     + (__expf(la[6] - ma) + __expf(la[7] - ma));
            float eb = (__expf(lb[0] - mb) + __expf(lb[1] - mb))
                     + (__expf(lb[2] - mb) + __expf(lb[3] - mb))
                     + (__expf(lb[4] - mb) + __expf(lb[5] - mb))
                     + (__expf(lb[6] - mb) + __expf(lb[7] - mb));
            #pragma unroll
            for (int off = 1; off <= 32; off <<= 1) {
                float ta = __shfl_xor(ea, off, 64);
                float tb = __shfl_xor(eb, off, 64);
                ea += ta;
                eb += tb;
            }

            wavesum += (ma + __logf(ea)) + (mb + __logf(eb));
        }
        if (lane == 0) wsum[wave] = wavesum;   // unique slot, no RMW
    } else {
        // rare: batch-boundary or ragged-tail wave -> per-point, atomics
        if (lane == 0) wsum[wave] = 0.0f;
        int cur_b = -1;
        for (int q = 0; q < PPW; ++q) {
            const int p = p0 + q;
            if (p >= n_pts) break;
            const int pb = batch[p];
            if (pb != cur_b) { build_from_global(pb); cur_b = pb; }
            float xv[6];
            const float* xp = x + (size_t)p * 6;
            #pragma unroll
            for (int d = 0; d < 6; ++d) xv[d] = xp[d];
            float l[KPL];
            logits(xv, l);
            float lm = local_max(l);
            #pragma unroll
            for (int off = 1; off <= 32; off <<= 1)
                lm = fmaxf(lm, __shfl_xor(lm, off, 64));
            float es = 0.0f;
            #pragma unroll
            for (int j = 0; j < KPL; ++j) es += __expf(l[j] - lm);
            #pragma unroll
            for (int off = 1; off <= 32; off <<= 1)
                es += __shfl_xor(es, off, 64);
            float lp = lm + __logf(es);
            if (lane == 0) atomicAdd(&out_pe[cur_b], lp);
        }
    }
}

// One block: reduce wsum[] per batch, fold boundary atomics, write mean.
__global__ __launch_bounds__(1024) void final_kernel(
    const float* __restrict__ wsum,
    const int* __restrict__ batch,
    float* __restrict__ d_out,   // [0]=mean, [1..32]=per-example
    int n_waves, int n_pts)
{
    __shared__ float part[NB];
    const int t = threadIdx.x;
    if (t < NB) part[t] = 0.0f;
    __syncthreads();

    for (int w = t; w < n_waves; w += 1024) {
        float s = wsum[w];                       // 0 for boundary waves
        int   pi = w * PPW;
        if (pi >= n_pts) pi = n_pts - 1;
        atomicAdd(&part[batch[pi]], s);          // LDS atomic, 32 bins
    }
    __syncthreads();

    if (t < 64) {
        float v = 0.0f;
        if (t < NB) {
            v = d_out[1 + t] + part[t];          // fold boundary atomics
            d_out[1 + t] = v;
        }
        #pragma unroll
        for (int off = 32; off >= 1; off >>= 1) v += __shfl_xor(v, off, 64);
        if (t == 0) d_out[0] = v * (1.0f / NB);
    }
}

extern "C" void kernel_launch(void* const* d_in, const int* in_sizes, int n_in,
                              void* d_out, int out_size, void* d_ws, size_t ws_size,
                              hipStream_t stream) {
    const float* x        = (const float*)d_in[0];
    const float* vote     = (const float*)d_in[1];
    const float* scales   = (const float*)d_in[2];
    const float* log_pres = (const float*)d_in[3];
    const int*   batch    = (const int*)d_in[4];
    float* out = (float*)d_out;
    float* ws  = (float*)d_ws;

    int n_pts   = in_sizes[0] / 6;
    int n_waves = (n_pts + PPW - 1) / PPW;

    // out re-poisoned to 0xAA before every timed call -> zero it (capture-legal)
    hipMemsetAsync(d_out, 0, (size_t)out_size * sizeof(float), stream);

    int n_blocks = (n_pts + PPB - 1) / PPB;  // 4 waves (256 threads) per block
    capsule_main<<<n_blocks, 256, 0, stream>>>(x, vote, scales, log_pres, batch,
                                               out + 1, ws, n_pts);

    final_kernel<<<1, 1024, 0, stream>>>(ws, batch, out, n_waves, n_pts);
}

// Round 20
// 92.099 us; speedup vs baseline: 1.0768x; 1.0045x over previous
//
#include <hip/hip_runtime.h>
#include <math.h>

#define LOG_2PI_F 1.8378770664093453f
#define EPS_F 1e-10f
#define NB 32        // batches
#define CV 512       // components per batch (C*V)
#define PPW 8        // points per wave
#define PPB 32       // points per block (4 waves)
#define KPL 8        // comps per lane = CV / 64

// r19 + x staged in the SAME block-start burst as params.
// Theory: kernel is cold-HBM-latency bound (harness 256MB fill wipes L2/L3
// every timed call; measured capsule hbm_gbps ~50-100 GB/s). One vectorized
// burst (13 float4/thread params + 48 float4 x) maximizes misses in flight;
// all later reads hit LDS.
__global__ __launch_bounds__(256)
__attribute__((amdgpu_waves_per_eu(2, 4)))
void capsule_main(
    const float* __restrict__ x,
    const float* __restrict__ vote,
    const float* __restrict__ scales,
    const float* __restrict__ log_pres,
    const int* __restrict__ batch,
    float* __restrict__ out_pe,   // [NB], zeroed; boundary waves atomic here
    float* __restrict__ wsum,     // [n_waves], unique slot per wave
    int n_pts)
{
    __shared__ float s_vote[CV * 6];    // 12 KB
    __shared__ float s_sc[CV];          // 2 KB
    __shared__ float s_lp[CV];          // 2 KB
    __shared__ float s_x[PPB * 6];      // 768 B

    const int tid  = threadIdx.x;
    const int lane = tid & 63;
    const int wloc = __builtin_amdgcn_readfirstlane(tid >> 6);
    const int wave = blockIdx.x * 4 + wloc;
    const int p0   = wave * PPW;

    // ---- one burst: params + x for the whole block ----
    int pblk = blockIdx.x * PPB;
    if (pblk >= n_pts) pblk = n_pts - 1;
    const int  bblk    = batch[pblk];
    const bool x_stged = (blockIdx.x * PPB + PPB <= n_pts);
    {
        const float4* gv = (const float4*)(vote + (size_t)bblk * CV * 6);
        float4* sv = (float4*)s_vote;
        #pragma unroll
        for (int i = 0; i < 3; ++i)            // 768 float4s / 256 threads
            sv[tid + 256 * i] = gv[tid + 256 * i];
        const float4* gs = (const float4*)(scales + (size_t)bblk * CV);
        const float4* gl = (const float4*)(log_pres + (size_t)bblk * CV);
        if (tid < 128) {
            ((float4*)s_sc)[tid] = gs[tid];
            ((float4*)s_lp)[tid] = gl[tid];
        }
        if (x_stged && tid < 48)               // 32 pts * 6 = 48 float4s
            ((float4*)s_x)[tid] =
                ((const float4*)(x + (size_t)blockIdx.x * PPB * 6))[tid];
    }
    __syncthreads();

    if (p0 >= n_pts) return;

    int pidx = p0 + (lane & (PPW - 1));
    if (pidx >= n_pts) pidx = n_pts - 1;
    const int  pbq     = batch[pidx];
    const int  b0      = __builtin_amdgcn_readfirstlane(pbq);
    const bool uniform = (__ballot(pbq == b0) == ~0ull) && (b0 == bblk)
                         && x_stged;

    // packed per-comp params in registers: a* = mu_d * inv, inv, coef
    float a0[KPL], a1[KPL], a2[KPL], a3[KPL], a4[KPL], a5[KPL];
    float ainv[KPL], acoef[KPL];

    auto build_from_lds = [&]() {
        #pragma unroll
        for (int j = 0; j < KPL; ++j) {
            const int c = lane + 64 * j;
            float s   = fmaxf(s_sc[c], EPS_F);
            float inv = 1.0f / s;
            const float* mu = s_vote + c * 6;
            a0[j] = mu[0] * inv;
            a1[j] = mu[1] * inv;
            a2[j] = mu[2] * inv;
            a3[j] = mu[3] * inv;
            a4[j] = mu[4] * inv;
            a5[j] = mu[5] * inv;
            ainv[j]  = inv;
            acoef[j] = s_lp[c] - 6.0f * __logf(s) - 3.0f * LOG_2PI_F;
        }
    };
    auto build_from_global = [&](int b) {
        #pragma unroll
        for (int j = 0; j < KPL; ++j) {
            const int c = b * CV + lane + 64 * j;
            float s   = fmaxf(scales[c], EPS_F);
            float inv = 1.0f / s;
            const float2* mu2 = (const float2*)(vote + (size_t)c * 6);
            float2 m01 = mu2[0], m23 = mu2[1], m45 = mu2[2];
            a0[j] = m01.x * inv;
            a1[j] = m01.y * inv;
            a2[j] = m23.x * inv;
            a3[j] = m23.y * inv;
            a4[j] = m45.x * inv;
            a5[j] = m45.y * inv;
            ainv[j]  = inv;
            acoef[j] = log_pres[c] - 6.0f * __logf(s) - 3.0f * LOG_2PI_F;
        }
    };

    auto logits = [&](const float* xv, float* l) {
        #pragma unroll
        for (int j = 0; j < KPL; ++j) {
            float z, acc;
            z = fmaf(xv[0], ainv[j], -a0[j]); acc = z * z;
            z = fmaf(xv[1], ainv[j], -a1[j]); acc = fmaf(z, z, acc);
            z = fmaf(xv[2], ainv[j], -a2[j]); acc = fmaf(z, z, acc);
            z = fmaf(xv[3], ainv[j], -a3[j]); acc = fmaf(z, z, acc);
            z = fmaf(xv[4], ainv[j], -a4[j]); acc = fmaf(z, z, acc);
            z = fmaf(xv[5], ainv[j], -a5[j]); acc = fmaf(z, z, acc);
            l[j] = fmaf(acc, -0.5f, acoef[j]);
        }
    };
    auto local_max = [](const float* l) {
        return fmaxf(fmaxf(fmaxf(l[0], l[1]), fmaxf(l[2], l[3])),
                     fmaxf(fmaxf(l[4], l[5]), fmaxf(l[6], l[7])));
    };

    if (uniform && p0 + PPW <= n_pts) {
        build_from_lds();
        const float* xw = s_x + wloc * PPW * 6;   // this wave's 8 points

        float wavesum = 0.0f;
        #pragma unroll
        for (int q = 0; q < PPW; q += 2) {
            float la[KPL], lb[KPL];
            logits(xw + q * 6,       la);
            logits(xw + (q + 1) * 6, lb);

            float ma = local_max(la);
            float mb = local_max(lb);
            #pragma unroll
            for (int off = 1; off <= 32; off <<= 1) {
                float ta = __shfl_xor(ma, off, 64);
                float tb = __shfl_xor(mb, off, 64);
                ma = fmaxf(ma, ta);
                mb = fmaxf(mb, tb);
            }

            float ea = (__expf(la[0] - ma) + __expf(la[1] - ma))
                     + (__expf(la[2] - ma) + __expf(la[3] - ma))
                     + (__expf(la[4] - ma) + __expf(la[5] - ma))
                     + (__expf(la[6] - ma) + __expf(la[7] - ma));
            float eb = (__expf(lb[0] - mb) + __expf(lb[1] - mb))
                     + (__expf(lb[2] - mb) + __expf(lb[3] - mb))
                     + (__expf(lb[4] - mb) + __expf(lb[5] - mb))
                     + (__expf(lb[6] - mb) + __expf(lb[7] - mb));
            #pragma unroll
            for (int off = 1; off <= 32; off <<= 1) {
                float ta = __shfl_xor(ea, off, 64);
                float tb = __shfl_xor(eb, off, 64);
                ea += ta;
                eb += tb;
            }

            wavesum += (ma + __logf(ea)) + (mb + __logf(eb));
        }
        if (lane == 0) wsum[wave] = wavesum;   // unique slot, no RMW
    } else {
        // rare: batch-boundary or ragged-tail wave -> per-point, atomics
        if (lane == 0) wsum[wave] = 0.0f;
        int cur_b = -1;
        for (int q = 0; q < PPW; ++q) {
            const int p = p0 + q;
            if (p >= n_pts) break;
            const int pb = batch[p];
            if (pb != cur_b) { build_from_global(pb); cur_b = pb; }
            float xv[6];
            const float* xp = x + (size_t)p * 6;
            #pragma unroll
            for (int d = 0; d < 6; ++d) xv[d] = xp[d];
            float l[KPL];
            logits(xv, l);
            float lm = local_max(l);
            #pragma unroll
            for (int off = 1; off <= 32; off <<= 1)
                lm = fmaxf(lm, __shfl_xor(lm, off, 64));
            float es = 0.0f;
            #pragma unroll
            for (int j = 0; j < KPL; ++j) es += __expf(l[j] - lm);
            #pragma unroll
            for (int off = 1; off <= 32; off <<= 1)
                es += __shfl_xor(es, off, 64);
            float lp = lm + __logf(es);
            if (lane == 0) atomicAdd(&out_pe[cur_b], lp);
        }
    }
}

// One block: reduce wsum[] per batch, fold boundary atomics, write mean.
__global__ __launch_bounds__(1024) void final_kernel(
    const float* __restrict__ wsum,
    const int* __restrict__ batch,
    float* __restrict__ d_out,   // [0]=mean, [1..32]=per-example
    int n_waves, int n_pts)
{
    __shared__ float part[NB];
    const int t = threadIdx.x;
    if (t < NB) part[t] = 0.0f;
    __syncthreads();

    for (int w = t; w < n_waves; w += 1024) {
        float s = wsum[w];                       // 0 for boundary waves
        int   pi = w * PPW;
        if (pi >= n_pts) pi = n_pts - 1;
        atomicAdd(&part[batch[pi]], s);          // LDS atomic, 32 bins
    }
    __syncthreads();

    if (t < 64) {
        float v = 0.0f;
        if (t < NB) {
            v = d_out[1 + t] + part[t];          // fold boundary atomics
            d_out[1 + t] = v;
        }
        #pragma unroll
        for (int off = 32; off >= 1; off >>= 1) v += __shfl_xor(v, off, 64);
        if (t == 0) d_out[0] = v * (1.0f / NB);
    }
}

extern "C" void kernel_launch(void* const* d_in, const int* in_sizes, int n_in,
                              void* d_out, int out_size, void* d_ws, size_t ws_size,
                              hipStream_t stream) {
    const float* x        = (const float*)d_in[0];
    const float* vote     = (const float*)d_in[1];
    const float* scales   = (const float*)d_in[2];
    const float* log_pres = (const float*)d_in[3];
    const int*   batch    = (const int*)d_in[4];
    float* out = (float*)d_out;
    float* ws  = (float*)d_ws;

    int n_pts   = in_sizes[0] / 6;
    int n_waves = (n_pts + PPW - 1) / PPW;

    // out re-poisoned to 0xAA before every timed call -> zero it (capture-legal)
    hipMemsetAsync(d_out, 0, (size_t)out_size * sizeof(float), stream);

    int n_blocks = (n_pts + PPB - 1) / PPB;  // 4 waves (256 threads) per block
    capsule_main<<<n_blocks, 256, 0, stream>>>(x, vote, scales, log_pres, batch,
                                               out + 1, ws, n_pts);

    final_kernel<<<1, 1024, 0, stream>>>(ws, batch, out, n_waves, n_pts);
}